// Round 11
// baseline (303.130 us; speedup 1.0000x reference)
//
#include <hip/hip_runtime.h>
#include <hip/hip_cooperative_groups.h>
#include <stdint.h>

namespace cg = cooperative_groups;

// ContinuousConvolution, MI355X gfx950. Round 21: launch-tax cut.
// knn + mlp reverted to R14 exactly (best measured, 141.7us; R15/R17/R19/
// R20 mlp/knn restructures all falsified). New: the 4 build dispatches
// (memset, pack_count, scan, scatter) fused into ONE cooperative kernel
// with grid.sync() phases — saves ~3 graph nodes x ~2-3us replay overhead.
// Phase math copied verbatim (zero -> pack/count -> 2-block 512-wide
// Hillis-Steele scan (256 thr, 2 elems/thr, same double-barrier order) ->
// scatter) -> outputs bit-identical.

typedef unsigned short u16;
typedef unsigned int   u32;
typedef unsigned long long u64;

#define NPTS  8192
#define KNB   16
#define SCAP  128   // survivors: E~20, n-independent
#define CAPA  512   // per-wave LDS point-cache: box ~432 +- 20, 512 = +4 sigma
#define QPW   8

__device__ __forceinline__ float bf2f(u16 u) {
    union { u32 i; float f; } v; v.i = ((u32)u) << 16; return v.f;
}
__device__ __forceinline__ u16 f2bf(float f) {
    u32 x = __float_as_uint(f);
    return (u16)((x + 0x7FFFu + ((x >> 16) & 1u)) >> 16);  // RNE (lossless here)
}
__device__ __forceinline__ u32 fordkey(float f) {
    u32 u = __float_as_uint(f);
    return u ^ ((u32)((int)u >> 31) | 0x80000000u);
}
__device__ __forceinline__ u64 shflxor64(u64 v, int m) {
    int lo = __shfl_xor((int)(u32)v, m, 64);
    int hi = __shfl_xor((int)(u32)(v >> 32), m, 64);
    return ((u64)(u32)hi << 32) | (u32)lo;
}
// Wave-internal LDS fence (rule #18 idiom).
__device__ __forceinline__ void wave_fence() {
    asm volatile("s_waitcnt lgkmcnt(0)" ::: "memory");
    __builtin_amdgcn_sched_barrier(0);
}
// Reference-matching d2 (verified round 5): dot = Eigen FMA chain, rest strict.
__device__ __forceinline__ float sq_np32(float x, float y, float z) {
    return __fadd_rn(__fadd_rn(__fmul_rn(x, x), __fmul_rn(y, y)), __fmul_rn(z, z));
}
__device__ __forceinline__ float d2_ref(float qx, float qy, float qz, float qsq,
                                        float x, float y, float z, float sq) {
    float dot = fmaf(z, qz, fmaf(y, qy, __fmul_rn(x, qx)));
    return __fsub_rn(__fadd_rn(qsq, sq), __fmul_rn(2.0f, dot));
}
__device__ __forceinline__ int cellof(float v) {
    int c = (int)floorf(v * 8.0f);
    return c < 0 ? 0 : (c > 7 ? 7 : c);
}

// ---------------- fused build kernel (cooperative, 512 x 256) ----------------
// P0 zero counts -> P1 pack pfh + count cells -> P2 scan (blocks 0,1) ->
// P3 scatter. All phases bit-identical to the former separate kernels.
__global__ __launch_bounds__(256) void build_kernel(
    const float* __restrict__ pf, const float* __restrict__ coords,
    u16* __restrict__ pfh, int* __restrict__ counts,
    int* __restrict__ cellStart, int* __restrict__ cellOffset,
    float4* __restrict__ spts, int* __restrict__ sidx) {
    cg::grid_group grid = cg::this_grid();
    __shared__ int s[512];

    const int t   = threadIdx.x;
    const int blk = blockIdx.x;
    const int g   = blk * 256 + t;            // 0..131071

    // P0: zero the 1024 count cells (replaces hipMemsetAsync).
    if (g < 1024) counts[g] = 0;
    grid.sync();

    // P1: pack 1,048,576 bf16 (stride-coalesced) + histogram 16384 points.
#pragma unroll
    for (int j = 0; j < 8; ++j) {
        int i = g + j * 131072;
        pfh[i] = f2bf(pf[i]);
    }
    if (g < 2 * NPTS) {
        float x = coords[g * 3 + 0];
        float y = coords[g * 3 + 1];
        float z = coords[g * 3 + 2];
        int b = g >> 13;
        int cell = (cellof(x) * 8 + cellof(y)) * 8 + cellof(z);
        atomicAdd(&counts[b * 512 + cell], 1);
    }
    grid.sync();

    // P2: inclusive scan of 512 counts per batch; blocks 0,1 (b = blk),
    // 256 threads x 2 elements, same read-barrier-write-barrier order as
    // the original 512-thread Hillis-Steele -> identical results.
    if (blk < 2) {
        const int b = blk;
        int c0 = counts[b * 512 + t];
        int c1 = counts[b * 512 + t + 256];
        s[t] = c0; s[t + 256] = c1;
        __syncthreads();
#pragma unroll
        for (int off = 1; off < 512; off <<= 1) {
            int v0 = (t >= off) ? s[t - off] : 0;
            int v1 = (t + 256 >= off) ? s[t + 256 - off] : 0;
            __syncthreads();
            s[t] += v0; s[t + 256] += v1;
            __syncthreads();
        }
        int e0 = s[t] - c0, e1 = s[t + 256] - c1;
        cellStart[b * 513 + t]        = e0;
        cellStart[b * 513 + t + 256]  = e1;
        cellOffset[b * 512 + t]       = e0;
        cellOffset[b * 512 + t + 256] = e1;
        if (t == 255) cellStart[b * 513 + 512] = s[511];
    }
    grid.sync();

    // P3: scatter (same as the former scatter_kernel).
    if (g < 2 * NPTS) {
        float x = coords[g * 3 + 0];
        float y = coords[g * 3 + 1];
        float z = coords[g * 3 + 2];
        int b = g >> 13, i = g & (NPTS - 1);
        int cell = (cellof(x) * 8 + cellof(y)) * 8 + cellof(z);
        int pos = atomicAdd(&cellOffset[b * 512 + cell], 1);
        spts[b * NPTS + pos] = make_float4(x, y, z, sq_np32(x, y, z));
        sidx[b * NPTS + pos] = i;
    }
}

// Stream global points of cells [z0..z1] in column `base`, compact survivors
// (d2 <= tau) into surv as (fordkey(d2)<<32 | sorted_pos).
__device__ __forceinline__ void scan_seg(
    const float4* __restrict__ sp, const int* __restrict__ cs,
    u64* __restrict__ surv, int base, int z0, int z1,
    float qx, float qy, float qz, float qsq, float tau, int lane, int& cnt) {
    if (z0 > z1) return;
    int s = cs[base + z0], e = cs[base + z1 + 1];
    for (int i0 = s; i0 < e; i0 += 64) {
        int i = i0 + lane;
        bool valid = (i < e);
        int ii = valid ? i : (e - 1);       // clamp: no OOB
        float4 c = sp[ii];
        float d2 = d2_ref(qx, qy, qz, qsq, c.x, c.y, c.z, c.w);
        bool pass = valid && (d2 <= tau);
        u64 mask = __ballot(pass);
        if (pass) {
            int pre = __builtin_amdgcn_mbcnt_hi((u32)(mask >> 32),
                      __builtin_amdgcn_mbcnt_lo((u32)mask, 0));
            int pos = cnt + pre;
            if (pos < SCAP)
                surv[pos] = ((u64)fordkey(d2) << 32) | (u32)ii;
        }
        cnt += (int)__popcll(mask);         // uniform across wave
    }
}

// ---------------- Kernel A: grid knn (4 independent waves / block) ----------
__global__ __launch_bounds__(256, 6) void knn_kernel(
    const float4* __restrict__ spts, const int* __restrict__ sidx,
    const int* __restrict__ cellStart, int* __restrict__ idx_out) {
    __shared__ u64 allk_s[4][CAPA];
    __shared__ u64 surv_s[4][SCAP];

    const int lane = threadIdx.x & 63;
    const int wid  = threadIdx.x >> 6;
    u64* __restrict__ allk = allk_s[wid];
    u64* __restrict__ surv = surv_s[wid];

    const int blk  = blockIdx.x;               // 0..4095
    // XCD chunk swizzle (grid 4096 = 8 * 512): each XCD gets a contiguous
    // sorted-query chunk -> candidate float4 stream L1/L2-resident.
    const int sblk = (blk & 7) * 512 + (blk >> 3);
    const int p    = sblk * 4 + wid;           // sorted position (1 per wave)
    const int b    = p >> 13;
    const float4* sp = spts + b * NPTS;
    const int*    si = sidx + b * NPTS;
    const int*    cs = cellStart + b * 513;

    float4 qc = sp[p & (NPTS - 1)];            // coords + |q|^2 (bit-identical)
    const float qx = qc.x, qy = qc.y, qz = qc.z, qsq = qc.w;
    int cqx = cellof(qx), cqy = cellof(qy), cqz = cellof(qz);

    // Query cell coords are wave-uniform (every lane loaded the same qc);
    // force them into the scalar domain so segment lookups become s_loads.
    const int ucqx = __builtin_amdgcn_readfirstlane(cqx);
    const int ucqy = __builtin_amdgcn_readfirstlane(cqy);
    const int ucqz = __builtin_amdgcn_readfirstlane(cqz);

    const int ax0 = max(ucqx - 1, 0), ax1 = min(ucqx + 1, 7);
    const int ay0 = max(ucqy - 1, 0), ay1 = min(ucqy + 1, 7);
    const int az0 = max(ucqz - 1, 0), az1 = min(ucqz + 1, 7);

    // Segment table: 9 fixed (cx,cy) slots, masked instead of clamped (same
    // point set, same stream order as iterating the in-range box). All 18
    // scalar loads issue together -> one latency, and Pass A below can
    // pipeline the point streams across columns.
    int segS[9], segE[9];
#pragma unroll
    for (int u = 0; u < 9; ++u) {
        int cx = ucqx - 1 + (u / 3);
        int cy = ucqy - 1 + (u % 3);
        bool ok = (cx >= 0) && (cx <= 7) && (cy >= 0) && (cy <= 7);
        if (ok) {
            int base = (cx * 8 + cy) * 8;
            segS[u] = cs[base + az0];
            segE[u] = cs[base + az1 + 1];
        } else {
            segS[u] = 0;
            segE[u] = 0;
        }
    }

    // PASS A: stream the 3x3x3 box ONCE; lane-minima for tau AND cache
    // (d2key, sorted_pos) in LDS for the filter phase. Fully unrolled over
    // the 9 segments so loads overlap (cnt0 dep is a cheap SALU add).
    float dmin = 3.0e38f;
    int cnt0 = 0;          // points cached in allk (wave-uniform)
    bool ovf = false;      // LDS cache overflow -> full global fallback
#pragma unroll
    for (int u = 0; u < 9; ++u) {
        int s = segS[u], e = segE[u];
#pragma unroll 1
        for (int i0 = s; i0 < e; i0 += 64) {
            int i = i0 + lane;
            bool valid = (i < e);
            int ii = valid ? i : (e - 1);     // clamp: no OOB
            float4 c = sp[ii];
            float d2 = d2_ref(qx, qy, qz, qsq, c.x, c.y, c.z, c.w);
            if (valid) dmin = fminf(dmin, d2);
            int add = (e - i0 < 64) ? (e - i0) : 64;
            if (!ovf && cnt0 + add <= CAPA) {
                if (valid)
                    allk[cnt0 + lane] = ((u64)fordkey(d2) << 32) | (u32)ii;
                cnt0 += add;                  // uniform
            } else {
                ovf = true;
            }
        }
    }
    wave_fence();   // allk visible to all lanes of this wave before filter

    {   // wave bitonic sort-64 ascending
        float v = dmin;
#pragma unroll
        for (int k = 2; k <= 64; k <<= 1) {
#pragma unroll
            for (int j2 = k >> 1; j2 >= 1; j2 >>= 1) {
                float o = __shfl_xor(v, j2, 64);
                bool lo = (lane & j2) == 0;
                bool up = (lane & k) == 0;
                float mn = fminf(v, o), mx = fmaxf(v, o);
                v = (lo == up) ? mn : mx;
            }
        }
        dmin = __shfl(v, 15, 64);          // 16th smallest lane-min
    }
    const float tau = dmin;                 // >= true 16th-NN d2

    // FILTER: compact survivors (d2 <= tau) from the LDS cache; key-domain
    // compare == float compare (fordkey monotone). Any point with d2 <= tau
    // lies inside the B-box, so the cached A-box plus the outside-A segments
    // below cover exactly the full-scan survivor set.
    float rr = sqrtf(tau + 1e-5f) + 1e-6f;
    int bx0 = max((int)floorf((qx - rr) * 8.0f), 0);
    int bx1 = min((int)floorf((qx + rr) * 8.0f), 7);
    int by0 = max((int)floorf((qy - rr) * 8.0f), 0);
    int by1 = min((int)floorf((qy + rr) * 8.0f), 7);
    int bz0 = max((int)floorf((qz - rr) * 8.0f), 0);
    int bz1 = min((int)floorf((qz + rr) * 8.0f), 7);
    int cnt = 0;
    if (!ovf) {
        const u32 taukey = fordkey(tau);
        for (int i0 = 0; i0 < cnt0; i0 += 64) {
            int i = i0 + lane;
            bool valid = (i < cnt0);
            u64 kk = valid ? allk[i] : ~0ull;
            bool pass = valid && ((u32)(kk >> 32) <= taukey);
            u64 mask = __ballot(pass);
            if (pass) {
                int pre = __builtin_amdgcn_mbcnt_hi((u32)(mask >> 32),
                          __builtin_amdgcn_mbcnt_lo((u32)mask, 0));
                int pos = cnt + pre;
                if (pos < SCAP) surv[pos] = kk;
            }
            cnt += (int)__popcll(mask);
        }
    }
    // Global scan of B-box cells not covered by the LDS cache (normally
    // zero segments; full B-box when ovf).
#pragma unroll 1
    for (int cx = bx0; cx <= bx1; ++cx)
#pragma unroll 1
        for (int cy = by0; cy <= by1; ++cy) {
            int base = (cx * 8 + cy) * 8;
            bool colInA = !ovf && cx >= ax0 && cx <= ax1 &&
                          cy >= ay0 && cy <= ay1;
            if (colInA) {
                scan_seg(sp, cs, surv, base, bz0, min(az0 - 1, bz1),
                         qx, qy, qz, qsq, tau, lane, cnt);
                scan_seg(sp, cs, surv, base, max(az1 + 1, bz0), bz1,
                         qx, qy, qz, qsq, tau, lane, cnt);
            } else {
                scan_seg(sp, cs, surv, base, bz0, bz1,
                         qx, qy, qz, qsq, tau, lane, cnt);
            }
        }
    wave_fence();   // surv visible to all lanes of this wave

    int myidx = 0;
    if (cnt <= 64) {
        // (key, payload) bitonic sort with LEXICOGRAPHIC compare — exactly
        // the u64 compare of R12 ((k<<32|p) < (ok<<32|op)), so tied d2 keys
        // are broken by payload and every pair is strictly ordered. Sentinel
        // lanes carry identical (0xffffffff, 0xffffffff) pairs — harmless.
        u32 k32 = 0xffffffffu, p32 = 0xffffffffu;
        if (lane < cnt) {
            u64 kk = surv[lane];
            k32 = (u32)(kk >> 32);
            p32 = (u32)kk;
        }
#pragma unroll
        for (int k = 2; k <= 64; k <<= 1) {
#pragma unroll
            for (int j2 = k >> 1; j2 >= 1; j2 >>= 1) {
                u32 ok = (u32)__shfl_xor((int)k32, j2, 64);
                u32 op = (u32)__shfl_xor((int)p32, j2, 64);
                bool lo = (lane & j2) == 0;
                bool up = (lane & k) == 0;
                bool takemin = (lo == up);
                bool less = (ok < k32) || (ok == k32 && op < p32);
                bool take = (less == takemin);
                k32 = take ? ok : k32;
                p32 = take ? op : p32;
            }
        }
        myidx = (int)p32;                      // sorted pos, lanes 0..15
    } else {
        int cc = cnt > SCAP ? SCAP : cnt;
        u64 a0 = (lane < cc) ? surv[lane] : ~0ull;
        u64 a1 = (64 + lane < cc) ? surv[64 + lane] : ~0ull;
        if (a1 < a0) { u64 tmp = a0; a0 = a1; a1 = tmp; }
#pragma unroll 1
        for (int r = 0; r < 16; ++r) {
            u64 m = a0;
#pragma unroll
            for (int d = 1; d < 64; d <<= 1) {
                u64 o = shflxor64(m, d);
                m = (o < m) ? o : m;
            }
            if (a0 == m) { a0 = a1; a1 = ~0ull; }
            if (lane == r) myidx = (int)(u32)(m & 0xffffffffu);
        }
    }
    if (lane < KNB) {
        const int q = si[p & (NPTS - 1)];      // original query id
        idx_out[((size_t)b * NPTS + q) * KNB + lane] =
            si[myidx & (NPTS - 1)];            // sorted pos -> original id
    }
}

// ---------------- Kernel B: gather + collapsed MLP, sorted order (R14) -----
// grid 2048 (= 8 XCD chunks x 256). Swizzle: hardware round-robins blk%8 ->
// XCD, so sblk = (blk&7)*256 + blk>>3 gives each XCD a CONTIGUOUS sorted-
// query chunk -> neighbor gathers hit that XCD's L2.
__global__ __launch_bounds__(64) void mlp_kernel(
    const u16* __restrict__ pfh, const float* __restrict__ coords,
    const float* __restrict__ w1, const float* __restrict__ b1,
    const float* __restrict__ w2, const float* __restrict__ b2,
    const float* __restrict__ w3, const float* __restrict__ b3,
    const float* __restrict__ aw, const float* __restrict__ ab,
    const int* __restrict__ knn_idx, const int* __restrict__ sidx,
    float* __restrict__ out) {

    __shared__ __attribute__((aligned(16))) float vbuf[2][68];
    __shared__ __attribute__((aligned(16))) float h1buf[2][36];

    const int lane = threadIdx.x;            // 0..63
    const int r    = lane & 31;
    const int vec  = lane >> 5;

    float w1r[68];
#pragma unroll
    for (int c = 0; c < 67; ++c) w1r[c] = w1[r * 67 + c];
    w1r[67] = 0.0f;
    float w2r[32];
    {
        const float4* p = (const float4*)(w2 + lane * 32);
#pragma unroll
        for (int c4 = 0; c4 < 8; ++c4) {
            float4 v = p[c4];
            w2r[c4 * 4 + 0] = v.x; w2r[c4 * 4 + 1] = v.y;
            w2r[c4 * 4 + 2] = v.z; w2r[c4 * 4 + 3] = v.w;
        }
    }
    float w3r[64];
    {
        const float4* p = (const float4*)(w3 + lane * 64);
#pragma unroll
        for (int c4 = 0; c4 < 16; ++c4) {
            float4 v = p[c4];
            w3r[c4 * 4 + 0] = v.x; w3r[c4 * 4 + 1] = v.y;
            w3r[c4 * 4 + 2] = v.z; w3r[c4 * 4 + 3] = v.w;
        }
    }
    float awr[16];
#pragma unroll
    for (int k = 0; k < 16; ++k) awr[k] = aw[k];
    float sa = 0.0f;
#pragma unroll
    for (int k = 0; k < 16; ++k) sa += awr[k];
    const float b1v = b1[r], b2v = b2[lane], b3v = b3[lane], abv = ab[0];
    const float c1 = (vec == 0) ? 16.0f : sa;

    // XCD-chunk swizzle (grid = 2048 = 8 * 256)
    const int sblk = (blockIdx.x & 7) * 256 + (blockIdx.x >> 3);

#pragma unroll 1
    for (int t = 0; t < QPW; ++t) {
        const int gp = sblk * QPW + t;        // global sorted position 0..16383
        const int b  = gp >> 13;
        const int q  = sidx[(size_t)b * NPTS + (gp & (NPTS - 1))];  // original id
        const int gq = b * NPTS + q;          // output/knn row
        const u16*   pfb = pfh + (size_t)b * NPTS * 64;
        const float* cb  = coords + (size_t)b * NPTS * 3;

        int myi = knn_idx[(size_t)gq * KNB + (lane & 15)] & (NPTS - 1);

        float pool = -3.0e38f, G1 = 0.0f, Ga = 0.0f;
#pragma unroll
        for (int k = 0; k < 16; ++k) {
            int nk = __shfl(myi, k, 64);
            float v = bf2f(pfb[nk * 64 + lane]);
            pool = fmaxf(pool, v);
            G1 += v;
            Ga = fmaf(awr[k], v, Ga);
        }
        vbuf[0][lane] = G1;
        vbuf[1][lane] = Ga;

        if (lane < 48) {
            int j  = lane >> 4;
            int i0 = __shfl(myi, 0, 64);
            float rel  = cb[myi * 3 + j] - cb[i0 * 3 + j];
            float wrel = awr[lane & 15] * rel;
#pragma unroll
            for (int d = 1; d < 16; d <<= 1) {
                rel  += __shfl_xor(rel, d, 64);
                wrel += __shfl_xor(wrel, d, 64);
            }
            if ((lane & 15) == 0) { vbuf[0][64 + j] = rel; vbuf[1][64 + j] = wrel; }
        }
        if (lane == 0) { vbuf[0][67] = 0.0f; vbuf[1][67] = 0.0f; }
        __syncthreads();

        float acc = c1 * b1v;
        {
            const float4* vp = (const float4*)(&vbuf[vec][0]);
#pragma unroll
            for (int c4 = 0; c4 < 17; ++c4) {
                float4 g4 = vp[c4];
                acc = fmaf(g4.x, w1r[c4 * 4 + 0], acc);
                acc = fmaf(g4.y, w1r[c4 * 4 + 1], acc);
                acc = fmaf(g4.z, w1r[c4 * 4 + 2], acc);
                acc = fmaf(g4.w, w1r[c4 * 4 + 3], acc);
            }
        }
        h1buf[vec][r] = acc;
        __syncthreads();

        float a0 = 16.0f * b2v, a1 = sa * b2v;
        {
            const float4* p0 = (const float4*)(&h1buf[0][0]);
            const float4* p1 = (const float4*)(&h1buf[1][0]);
#pragma unroll
            for (int c4 = 0; c4 < 8; ++c4) {
                float4 x0 = p0[c4], x1 = p1[c4];
                a0 = fmaf(x0.x, w2r[c4 * 4 + 0], a0);
                a0 = fmaf(x0.y, w2r[c4 * 4 + 1], a0);
                a0 = fmaf(x0.z, w2r[c4 * 4 + 2], a0);
                a0 = fmaf(x0.w, w2r[c4 * 4 + 3], a0);
                a1 = fmaf(x1.x, w2r[c4 * 4 + 0], a1);
                a1 = fmaf(x1.y, w2r[c4 * 4 + 1], a1);
                a1 = fmaf(x1.z, w2r[c4 * 4 + 2], a1);
                a1 = fmaf(x1.w, w2r[c4 * 4 + 3], a1);
            }
        }
        __syncthreads();
        vbuf[0][lane] = a0;
        vbuf[1][lane] = a1;
        __syncthreads();

        float s1 = 16.0f * b3v, sA = sa * b3v;
        {
            const float4* p0 = (const float4*)(&vbuf[0][0]);
            const float4* p1 = (const float4*)(&vbuf[1][0]);
#pragma unroll
            for (int c4 = 0; c4 < 16; ++c4) {
                float4 x0 = p0[c4], x1 = p1[c4];
                s1 = fmaf(x0.x, w3r[c4 * 4 + 0], s1);
                s1 = fmaf(x0.y, w3r[c4 * 4 + 1], s1);
                s1 = fmaf(x0.z, w3r[c4 * 4 + 2], s1);
                s1 = fmaf(x0.w, w3r[c4 * 4 + 3], s1);
                sA = fmaf(x1.x, w3r[c4 * 4 + 0], sA);
                sA = fmaf(x1.y, w3r[c4 * 4 + 1], sA);
                sA = fmaf(x1.z, w3r[c4 * 4 + 2], sA);
                sA = fmaf(x1.w, w3r[c4 * 4 + 3], sA);
            }
        }
        float* op = out + (size_t)gq * 192;
        op[lane]       = s1;
        op[64 + lane]  = pool;
        op[128 + lane] = sA + abv;
        __syncthreads();
    }
}

extern "C" void kernel_launch(void* const* d_in, const int* in_sizes, int n_in,
                              void* d_out, int out_size, void* d_ws, size_t ws_size,
                              hipStream_t stream) {
    const float* pf     = (const float*)d_in[0];
    const float* coords = (const float*)d_in[1];
    const float* w1     = (const float*)d_in[2];
    const float* b1     = (const float*)d_in[3];
    const float* w2     = (const float*)d_in[4];
    const float* b2     = (const float*)d_in[5];
    const float* w3     = (const float*)d_in[6];
    const float* b3     = (const float*)d_in[7];
    const float* aw     = (const float*)d_in[8];
    const float* ab     = (const float*)d_in[9];

    char* ws = (char*)d_ws;
    int*    knn_idx    = (int*)ws;                              // 1 MB
    u16*    pfh        = (u16*)(ws + (1 << 20));                // 2 MB
    float4* spts       = (float4*)(ws + (3 << 20));             // 256 KB
    int*    sidx       = (int*)(ws + (3 << 20) + (256 << 10));  // 64 KB
    int*    cellStart  = (int*)(ws + (3 << 20) + (320 << 10));  // 2*513*4 B
    int*    counts     = (int*)(ws + (3 << 20) + (328 << 10));  // 2*512*4 B
    int*    cellOffset = (int*)(ws + (3 << 20) + (336 << 10));  // 2*512*4 B
    float*  outp       = (float*)d_out;

    void* bargs[] = {
        (void*)&pf, (void*)&coords, (void*)&pfh, (void*)&counts,
        (void*)&cellStart, (void*)&cellOffset, (void*)&spts, (void*)&sidx
    };
    hipLaunchCooperativeKernel((void*)build_kernel, dim3(512), dim3(256),
                               bargs, 0, stream);
    knn_kernel<<<4096, 256, 0, stream>>>(spts, sidx, cellStart, knn_idx);
    mlp_kernel<<<2048, 64, 0, stream>>>(pfh, coords, w1, b1, w2, b2, w3, b3,
                                        aw, ab, knn_idx, sidx, outp);
}

// Round 12
// 141.234 us; speedup vs baseline: 2.1463x; 2.1463x over previous
//
#include <hip/hip_runtime.h>
#include <stdint.h>

// ContinuousConvolution, MI355X gfx950. Round 22: REVERT to R14 exactly
// (best measured: 141.66us). R21's coop build_kernel was 150us by itself —
// grid.sync() on a 512-block grid costs ~40-50us per barrier on MI355X,
// ~20x the graph-node overhead it was meant to save. Falsified levers so
// far: knn sort-ILP (R15), mlp grid scaling (R17), mlp launch_bounds clamp
// (R19), mlp 4-wave shared stage (R20), build fusion (R21). R14 stands.

typedef unsigned short u16;
typedef unsigned int   u32;
typedef unsigned long long u64;

#define NPTS  8192
#define KNB   16
#define SCAP  128   // survivors: E~20, n-independent
#define CAPA  512   // per-wave LDS point-cache: box ~432 +- 20, 512 = +4 sigma
#define QPW   8

__device__ __forceinline__ float bf2f(u16 u) {
    union { u32 i; float f; } v; v.i = ((u32)u) << 16; return v.f;
}
__device__ __forceinline__ u16 f2bf(float f) {
    u32 x = __float_as_uint(f);
    return (u16)((x + 0x7FFFu + ((x >> 16) & 1u)) >> 16);  // RNE (lossless here)
}
__device__ __forceinline__ u32 fordkey(float f) {
    u32 u = __float_as_uint(f);
    return u ^ ((u32)((int)u >> 31) | 0x80000000u);
}
__device__ __forceinline__ u64 shflxor64(u64 v, int m) {
    int lo = __shfl_xor((int)(u32)v, m, 64);
    int hi = __shfl_xor((int)(u32)(v >> 32), m, 64);
    return ((u64)(u32)hi << 32) | (u32)lo;
}
// Wave-internal LDS fence (rule #18 idiom).
__device__ __forceinline__ void wave_fence() {
    asm volatile("s_waitcnt lgkmcnt(0)" ::: "memory");
    __builtin_amdgcn_sched_barrier(0);
}
// Reference-matching d2 (verified round 5): dot = Eigen FMA chain, rest strict.
__device__ __forceinline__ float sq_np32(float x, float y, float z) {
    return __fadd_rn(__fadd_rn(__fmul_rn(x, x), __fmul_rn(y, y)), __fmul_rn(z, z));
}
__device__ __forceinline__ float d2_ref(float qx, float qy, float qz, float qsq,
                                        float x, float y, float z, float sq) {
    float dot = fmaf(z, qz, fmaf(y, qy, __fmul_rn(x, qx)));
    return __fsub_rn(__fadd_rn(qsq, sq), __fmul_rn(2.0f, dot));
}
__device__ __forceinline__ int cellof(float v) {
    int c = (int)floorf(v * 8.0f);
    return c < 0 ? 0 : (c > 7 ? 7 : c);
}

// ---------------- build kernels ----------------
__global__ __launch_bounds__(256) void pack_count_kernel(
    const float* __restrict__ pf, const float* __restrict__ coords,
    u16* __restrict__ pfh, int* __restrict__ counts) {
    int gid = blockIdx.x * 256 + threadIdx.x;     // 0..1048575
    pfh[gid] = f2bf(pf[gid]);
    if (gid < 2 * NPTS) {
        float x = coords[gid * 3 + 0];
        float y = coords[gid * 3 + 1];
        float z = coords[gid * 3 + 2];
        int b = gid >> 13;
        int cell = (cellof(x) * 8 + cellof(y)) * 8 + cellof(z);
        atomicAdd(&counts[b * 512 + cell], 1);
    }
}

__global__ __launch_bounds__(512) void scan_kernel(
    const int* __restrict__ counts, int* __restrict__ cellStart,
    int* __restrict__ cellOffset) {
    __shared__ int s[512];
    int b = blockIdx.x, t = threadIdx.x;
    int myc = counts[b * 512 + t];
    s[t] = myc; __syncthreads();
#pragma unroll
    for (int off = 1; off < 512; off <<= 1) {
        int v = (t >= off) ? s[t - off] : 0; __syncthreads();
        s[t] += v; __syncthreads();
    }
    int excl = s[t] - myc;
    cellStart[b * 513 + t] = excl;
    cellOffset[b * 512 + t] = excl;
    if (t == 511) cellStart[b * 513 + 512] = s[511];
}

__global__ __launch_bounds__(256) void scatter_kernel(
    const float* __restrict__ coords, int* __restrict__ cellOffset,
    float4* __restrict__ spts, int* __restrict__ sidx) {
    int gid = blockIdx.x * 256 + threadIdx.x;     // 0..16383
    float x = coords[gid * 3 + 0];
    float y = coords[gid * 3 + 1];
    float z = coords[gid * 3 + 2];
    int b = gid >> 13, i = gid & (NPTS - 1);
    int cell = (cellof(x) * 8 + cellof(y)) * 8 + cellof(z);
    int pos = atomicAdd(&cellOffset[b * 512 + cell], 1);
    spts[b * NPTS + pos] = make_float4(x, y, z, sq_np32(x, y, z));
    sidx[b * NPTS + pos] = i;
}

// Stream global points of cells [z0..z1] in column `base`, compact survivors
// (d2 <= tau) into surv as (fordkey(d2)<<32 | sorted_pos).
__device__ __forceinline__ void scan_seg(
    const float4* __restrict__ sp, const int* __restrict__ cs,
    u64* __restrict__ surv, int base, int z0, int z1,
    float qx, float qy, float qz, float qsq, float tau, int lane, int& cnt) {
    if (z0 > z1) return;
    int s = cs[base + z0], e = cs[base + z1 + 1];
    for (int i0 = s; i0 < e; i0 += 64) {
        int i = i0 + lane;
        bool valid = (i < e);
        int ii = valid ? i : (e - 1);       // clamp: no OOB
        float4 c = sp[ii];
        float d2 = d2_ref(qx, qy, qz, qsq, c.x, c.y, c.z, c.w);
        bool pass = valid && (d2 <= tau);
        u64 mask = __ballot(pass);
        if (pass) {
            int pre = __builtin_amdgcn_mbcnt_hi((u32)(mask >> 32),
                      __builtin_amdgcn_mbcnt_lo((u32)mask, 0));
            int pos = cnt + pre;
            if (pos < SCAP)
                surv[pos] = ((u64)fordkey(d2) << 32) | (u32)ii;
        }
        cnt += (int)__popcll(mask);         // uniform across wave
    }
}

// ---------------- Kernel A: grid knn (4 independent waves / block) ----------
__global__ __launch_bounds__(256, 6) void knn_kernel(
    const float4* __restrict__ spts, const int* __restrict__ sidx,
    const int* __restrict__ cellStart, int* __restrict__ idx_out) {
    __shared__ u64 allk_s[4][CAPA];
    __shared__ u64 surv_s[4][SCAP];

    const int lane = threadIdx.x & 63;
    const int wid  = threadIdx.x >> 6;
    u64* __restrict__ allk = allk_s[wid];
    u64* __restrict__ surv = surv_s[wid];

    const int blk  = blockIdx.x;               // 0..4095
    // XCD chunk swizzle (grid 4096 = 8 * 512): each XCD gets a contiguous
    // sorted-query chunk -> candidate float4 stream L1/L2-resident.
    const int sblk = (blk & 7) * 512 + (blk >> 3);
    const int p    = sblk * 4 + wid;           // sorted position (1 per wave)
    const int b    = p >> 13;
    const float4* sp = spts + b * NPTS;
    const int*    si = sidx + b * NPTS;
    const int*    cs = cellStart + b * 513;

    float4 qc = sp[p & (NPTS - 1)];            // coords + |q|^2 (bit-identical)
    const float qx = qc.x, qy = qc.y, qz = qc.z, qsq = qc.w;
    int cqx = cellof(qx), cqy = cellof(qy), cqz = cellof(qz);

    // Query cell coords are wave-uniform (every lane loaded the same qc);
    // force them into the scalar domain so segment lookups become s_loads.
    const int ucqx = __builtin_amdgcn_readfirstlane(cqx);
    const int ucqy = __builtin_amdgcn_readfirstlane(cqy);
    const int ucqz = __builtin_amdgcn_readfirstlane(cqz);

    const int ax0 = max(ucqx - 1, 0), ax1 = min(ucqx + 1, 7);
    const int ay0 = max(ucqy - 1, 0), ay1 = min(ucqy + 1, 7);
    const int az0 = max(ucqz - 1, 0), az1 = min(ucqz + 1, 7);

    // Segment table: 9 fixed (cx,cy) slots, masked instead of clamped (same
    // point set, same stream order as iterating the in-range box). All 18
    // scalar loads issue together -> one latency, and Pass A below can
    // pipeline the point streams across columns.
    int segS[9], segE[9];
#pragma unroll
    for (int u = 0; u < 9; ++u) {
        int cx = ucqx - 1 + (u / 3);
        int cy = ucqy - 1 + (u % 3);
        bool ok = (cx >= 0) && (cx <= 7) && (cy >= 0) && (cy <= 7);
        if (ok) {
            int base = (cx * 8 + cy) * 8;
            segS[u] = cs[base + az0];
            segE[u] = cs[base + az1 + 1];
        } else {
            segS[u] = 0;
            segE[u] = 0;
        }
    }

    // PASS A: stream the 3x3x3 box ONCE; lane-minima for tau AND cache
    // (d2key, sorted_pos) in LDS for the filter phase. Fully unrolled over
    // the 9 segments so loads overlap (cnt0 dep is a cheap SALU add).
    float dmin = 3.0e38f;
    int cnt0 = 0;          // points cached in allk (wave-uniform)
    bool ovf = false;      // LDS cache overflow -> full global fallback
#pragma unroll
    for (int u = 0; u < 9; ++u) {
        int s = segS[u], e = segE[u];
#pragma unroll 1
        for (int i0 = s; i0 < e; i0 += 64) {
            int i = i0 + lane;
            bool valid = (i < e);
            int ii = valid ? i : (e - 1);     // clamp: no OOB
            float4 c = sp[ii];
            float d2 = d2_ref(qx, qy, qz, qsq, c.x, c.y, c.z, c.w);
            if (valid) dmin = fminf(dmin, d2);
            int add = (e - i0 < 64) ? (e - i0) : 64;
            if (!ovf && cnt0 + add <= CAPA) {
                if (valid)
                    allk[cnt0 + lane] = ((u64)fordkey(d2) << 32) | (u32)ii;
                cnt0 += add;                  // uniform
            } else {
                ovf = true;
            }
        }
    }
    wave_fence();   // allk visible to all lanes of this wave before filter

    {   // wave bitonic sort-64 ascending
        float v = dmin;
#pragma unroll
        for (int k = 2; k <= 64; k <<= 1) {
#pragma unroll
            for (int j2 = k >> 1; j2 >= 1; j2 >>= 1) {
                float o = __shfl_xor(v, j2, 64);
                bool lo = (lane & j2) == 0;
                bool up = (lane & k) == 0;
                float mn = fminf(v, o), mx = fmaxf(v, o);
                v = (lo == up) ? mn : mx;
            }
        }
        dmin = __shfl(v, 15, 64);          // 16th smallest lane-min
    }
    const float tau = dmin;                 // >= true 16th-NN d2

    // FILTER: compact survivors (d2 <= tau) from the LDS cache; key-domain
    // compare == float compare (fordkey monotone). Any point with d2 <= tau
    // lies inside the B-box, so the cached A-box plus the outside-A segments
    // below cover exactly the full-scan survivor set.
    float rr = sqrtf(tau + 1e-5f) + 1e-6f;
    int bx0 = max((int)floorf((qx - rr) * 8.0f), 0);
    int bx1 = min((int)floorf((qx + rr) * 8.0f), 7);
    int by0 = max((int)floorf((qy - rr) * 8.0f), 0);
    int by1 = min((int)floorf((qy + rr) * 8.0f), 7);
    int bz0 = max((int)floorf((qz - rr) * 8.0f), 0);
    int bz1 = min((int)floorf((qz + rr) * 8.0f), 7);
    int cnt = 0;
    if (!ovf) {
        const u32 taukey = fordkey(tau);
        for (int i0 = 0; i0 < cnt0; i0 += 64) {
            int i = i0 + lane;
            bool valid = (i < cnt0);
            u64 kk = valid ? allk[i] : ~0ull;
            bool pass = valid && ((u32)(kk >> 32) <= taukey);
            u64 mask = __ballot(pass);
            if (pass) {
                int pre = __builtin_amdgcn_mbcnt_hi((u32)(mask >> 32),
                          __builtin_amdgcn_mbcnt_lo((u32)mask, 0));
                int pos = cnt + pre;
                if (pos < SCAP) surv[pos] = kk;
            }
            cnt += (int)__popcll(mask);
        }
    }
    // Global scan of B-box cells not covered by the LDS cache (normally
    // zero segments; full B-box when ovf).
#pragma unroll 1
    for (int cx = bx0; cx <= bx1; ++cx)
#pragma unroll 1
        for (int cy = by0; cy <= by1; ++cy) {
            int base = (cx * 8 + cy) * 8;
            bool colInA = !ovf && cx >= ax0 && cx <= ax1 &&
                          cy >= ay0 && cy <= ay1;
            if (colInA) {
                scan_seg(sp, cs, surv, base, bz0, min(az0 - 1, bz1),
                         qx, qy, qz, qsq, tau, lane, cnt);
                scan_seg(sp, cs, surv, base, max(az1 + 1, bz0), bz1,
                         qx, qy, qz, qsq, tau, lane, cnt);
            } else {
                scan_seg(sp, cs, surv, base, bz0, bz1,
                         qx, qy, qz, qsq, tau, lane, cnt);
            }
        }
    wave_fence();   // surv visible to all lanes of this wave

    int myidx = 0;
    if (cnt <= 64) {
        // (key, payload) bitonic sort with LEXICOGRAPHIC compare — exactly
        // the u64 compare of R12 ((k<<32|p) < (ok<<32|op)), so tied d2 keys
        // are broken by payload and every pair is strictly ordered. Sentinel
        // lanes carry identical (0xffffffff, 0xffffffff) pairs — harmless.
        u32 k32 = 0xffffffffu, p32 = 0xffffffffu;
        if (lane < cnt) {
            u64 kk = surv[lane];
            k32 = (u32)(kk >> 32);
            p32 = (u32)kk;
        }
#pragma unroll
        for (int k = 2; k <= 64; k <<= 1) {
#pragma unroll
            for (int j2 = k >> 1; j2 >= 1; j2 >>= 1) {
                u32 ok = (u32)__shfl_xor((int)k32, j2, 64);
                u32 op = (u32)__shfl_xor((int)p32, j2, 64);
                bool lo = (lane & j2) == 0;
                bool up = (lane & k) == 0;
                bool takemin = (lo == up);
                bool less = (ok < k32) || (ok == k32 && op < p32);
                bool take = (less == takemin);
                k32 = take ? ok : k32;
                p32 = take ? op : p32;
            }
        }
        myidx = (int)p32;                      // sorted pos, lanes 0..15
    } else {
        int cc = cnt > SCAP ? SCAP : cnt;
        u64 a0 = (lane < cc) ? surv[lane] : ~0ull;
        u64 a1 = (64 + lane < cc) ? surv[64 + lane] : ~0ull;
        if (a1 < a0) { u64 tmp = a0; a0 = a1; a1 = tmp; }
#pragma unroll 1
        for (int r = 0; r < 16; ++r) {
            u64 m = a0;
#pragma unroll
            for (int d = 1; d < 64; d <<= 1) {
                u64 o = shflxor64(m, d);
                m = (o < m) ? o : m;
            }
            if (a0 == m) { a0 = a1; a1 = ~0ull; }
            if (lane == r) myidx = (int)(u32)(m & 0xffffffffu);
        }
    }
    if (lane < KNB) {
        const int q = si[p & (NPTS - 1)];      // original query id
        idx_out[((size_t)b * NPTS + q) * KNB + lane] =
            si[myidx & (NPTS - 1)];            // sorted pos -> original id
    }
}

// ---------------- Kernel B: gather + collapsed MLP, sorted order ----------------
// grid 2048 (= 8 XCD chunks x 256). Swizzle: hardware round-robins blk%8 -> XCD,
// so sblk = (blk&7)*256 + blk>>3 gives each XCD a CONTIGUOUS sorted-query chunk
// -> neighbor gathers hit that XCD's L2 (working set ~0.5 MB + halo << 4 MB).
__global__ __launch_bounds__(64) void mlp_kernel(
    const u16* __restrict__ pfh, const float* __restrict__ coords,
    const float* __restrict__ w1, const float* __restrict__ b1,
    const float* __restrict__ w2, const float* __restrict__ b2,
    const float* __restrict__ w3, const float* __restrict__ b3,
    const float* __restrict__ aw, const float* __restrict__ ab,
    const int* __restrict__ knn_idx, const int* __restrict__ sidx,
    float* __restrict__ out) {

    __shared__ __attribute__((aligned(16))) float vbuf[2][68];
    __shared__ __attribute__((aligned(16))) float h1buf[2][36];

    const int lane = threadIdx.x;            // 0..63
    const int r    = lane & 31;
    const int vec  = lane >> 5;

    float w1r[68];
#pragma unroll
    for (int c = 0; c < 67; ++c) w1r[c] = w1[r * 67 + c];
    w1r[67] = 0.0f;
    float w2r[32];
    {
        const float4* p = (const float4*)(w2 + lane * 32);
#pragma unroll
        for (int c4 = 0; c4 < 8; ++c4) {
            float4 v = p[c4];
            w2r[c4 * 4 + 0] = v.x; w2r[c4 * 4 + 1] = v.y;
            w2r[c4 * 4 + 2] = v.z; w2r[c4 * 4 + 3] = v.w;
        }
    }
    float w3r[64];
    {
        const float4* p = (const float4*)(w3 + lane * 64);
#pragma unroll
        for (int c4 = 0; c4 < 16; ++c4) {
            float4 v = p[c4];
            w3r[c4 * 4 + 0] = v.x; w3r[c4 * 4 + 1] = v.y;
            w3r[c4 * 4 + 2] = v.z; w3r[c4 * 4 + 3] = v.w;
        }
    }
    float awr[16];
#pragma unroll
    for (int k = 0; k < 16; ++k) awr[k] = aw[k];
    float sa = 0.0f;
#pragma unroll
    for (int k = 0; k < 16; ++k) sa += awr[k];
    const float b1v = b1[r], b2v = b2[lane], b3v = b3[lane], abv = ab[0];
    const float c1 = (vec == 0) ? 16.0f : sa;

    // XCD-chunk swizzle (grid = 2048 = 8 * 256)
    const int sblk = (blockIdx.x & 7) * 256 + (blockIdx.x >> 3);

#pragma unroll 1
    for (int t = 0; t < QPW; ++t) {
        const int gp = sblk * QPW + t;        // global sorted position 0..16383
        const int b  = gp >> 13;
        const int q  = sidx[(size_t)b * NPTS + (gp & (NPTS - 1))];  // original id
        const int gq = b * NPTS + q;          // output/knn row
        const u16*   pfb = pfh + (size_t)b * NPTS * 64;
        const float* cb  = coords + (size_t)b * NPTS * 3;

        int myi = knn_idx[(size_t)gq * KNB + (lane & 15)] & (NPTS - 1);

        float pool = -3.0e38f, G1 = 0.0f, Ga = 0.0f;
#pragma unroll
        for (int k = 0; k < 16; ++k) {
            int nk = __shfl(myi, k, 64);
            float v = bf2f(pfb[nk * 64 + lane]);
            pool = fmaxf(pool, v);
            G1 += v;
            Ga = fmaf(awr[k], v, Ga);
        }
        vbuf[0][lane] = G1;
        vbuf[1][lane] = Ga;

        if (lane < 48) {
            int j  = lane >> 4;
            int i0 = __shfl(myi, 0, 64);
            float rel  = cb[myi * 3 + j] - cb[i0 * 3 + j];
            float wrel = awr[lane & 15] * rel;
#pragma unroll
            for (int d = 1; d < 16; d <<= 1) {
                rel  += __shfl_xor(rel, d, 64);
                wrel += __shfl_xor(wrel, d, 64);
            }
            if ((lane & 15) == 0) { vbuf[0][64 + j] = rel; vbuf[1][64 + j] = wrel; }
        }
        if (lane == 0) { vbuf[0][67] = 0.0f; vbuf[1][67] = 0.0f; }
        __syncthreads();

        float acc = c1 * b1v;
        {
            const float4* vp = (const float4*)(&vbuf[vec][0]);
#pragma unroll
            for (int c4 = 0; c4 < 17; ++c4) {
                float4 g4 = vp[c4];
                acc = fmaf(g4.x, w1r[c4 * 4 + 0], acc);
                acc = fmaf(g4.y, w1r[c4 * 4 + 1], acc);
                acc = fmaf(g4.z, w1r[c4 * 4 + 2], acc);
                acc = fmaf(g4.w, w1r[c4 * 4 + 3], acc);
            }
        }
        h1buf[vec][r] = acc;
        __syncthreads();

        float a0 = 16.0f * b2v, a1 = sa * b2v;
        {
            const float4* p0 = (const float4*)(&h1buf[0][0]);
            const float4* p1 = (const float4*)(&h1buf[1][0]);
#pragma unroll
            for (int c4 = 0; c4 < 8; ++c4) {
                float4 x0 = p0[c4], x1 = p1[c4];
                a0 = fmaf(x0.x, w2r[c4 * 4 + 0], a0);
                a0 = fmaf(x0.y, w2r[c4 * 4 + 1], a0);
                a0 = fmaf(x0.z, w2r[c4 * 4 + 2], a0);
                a0 = fmaf(x0.w, w2r[c4 * 4 + 3], a0);
                a1 = fmaf(x1.x, w2r[c4 * 4 + 0], a1);
                a1 = fmaf(x1.y, w2r[c4 * 4 + 1], a1);
                a1 = fmaf(x1.z, w2r[c4 * 4 + 2], a1);
                a1 = fmaf(x1.w, w2r[c4 * 4 + 3], a1);
            }
        }
        __syncthreads();
        vbuf[0][lane] = a0;
        vbuf[1][lane] = a1;
        __syncthreads();

        float s1 = 16.0f * b3v, sA = sa * b3v;
        {
            const float4* p0 = (const float4*)(&vbuf[0][0]);
            const float4* p1 = (const float4*)(&vbuf[1][0]);
#pragma unroll
            for (int c4 = 0; c4 < 16; ++c4) {
                float4 x0 = p0[c4], x1 = p1[c4];
                s1 = fmaf(x0.x, w3r[c4 * 4 + 0], s1);
                s1 = fmaf(x0.y, w3r[c4 * 4 + 1], s1);
                s1 = fmaf(x0.z, w3r[c4 * 4 + 2], s1);
                s1 = fmaf(x0.w, w3r[c4 * 4 + 3], s1);
                sA = fmaf(x1.x, w3r[c4 * 4 + 0], sA);
                sA = fmaf(x1.y, w3r[c4 * 4 + 1], sA);
                sA = fmaf(x1.z, w3r[c4 * 4 + 2], sA);
                sA = fmaf(x1.w, w3r[c4 * 4 + 3], sA);
            }
        }
        float* op = out + (size_t)gq * 192;
        op[lane]       = s1;
        op[64 + lane]  = pool;
        op[128 + lane] = sA + abv;
        __syncthreads();
    }
}

extern "C" void kernel_launch(void* const* d_in, const int* in_sizes, int n_in,
                              void* d_out, int out_size, void* d_ws, size_t ws_size,
                              hipStream_t stream) {
    const float* pf     = (const float*)d_in[0];
    const float* coords = (const float*)d_in[1];
    const float* w1     = (const float*)d_in[2];
    const float* b1     = (const float*)d_in[3];
    const float* w2     = (const float*)d_in[4];
    const float* b2     = (const float*)d_in[5];
    const float* w3     = (const float*)d_in[6];
    const float* b3     = (const float*)d_in[7];
    const float* aw     = (const float*)d_in[8];
    const float* ab     = (const float*)d_in[9];

    char* ws = (char*)d_ws;
    int*    knn_idx    = (int*)ws;                              // 1 MB
    u16*    pfh        = (u16*)(ws + (1 << 20));                // 2 MB
    float4* spts       = (float4*)(ws + (3 << 20));             // 256 KB
    int*    sidx       = (int*)(ws + (3 << 20) + (256 << 10));  // 64 KB
    int*    cellStart  = (int*)(ws + (3 << 20) + (320 << 10));  // 2*513*4 B
    int*    counts     = (int*)(ws + (3 << 20) + (328 << 10));  // 2*512*4 B
    int*    cellOffset = (int*)(ws + (3 << 20) + (336 << 10));  // 2*512*4 B
    float*  outp       = (float*)d_out;

    hipMemsetAsync(counts, 0, 2 * 512 * sizeof(int), stream);
    pack_count_kernel<<<4096, 256, 0, stream>>>(pf, coords, pfh, counts);
    scan_kernel<<<2, 512, 0, stream>>>(counts, cellStart, cellOffset);
    scatter_kernel<<<64, 256, 0, stream>>>(coords, cellOffset, spts, sidx);
    knn_kernel<<<4096, 256, 0, stream>>>(spts, sidx, cellStart, knn_idx);
    mlp_kernel<<<2048, 64, 0, stream>>>(pfh, coords, w1, b1, w2, b2, w3, b3,
                                        aw, ab, knn_idx, sidx, outp);
}